// Round 14
// baseline (65.453 us; speedup 1.0000x reference)
//
#include <hip/hip_runtime.h>

// Problem constants (from reference)
#define NNODES 10000
#define DDEG   64
#define NEDGES 32768
#define FIN    64
#define HID    256

typedef __attribute__((ext_vector_type(8))) __bf16 bf16x8;
typedef __attribute__((ext_vector_type(4))) float  f32x4;

__device__ __forceinline__ unsigned short f2bf(float f) {
    unsigned x = __float_as_uint(f);
    return (unsigned short)((x + 0x7FFFu + ((x >> 16) & 1u)) >> 16);  // RNE
}
__device__ __forceinline__ float b2f(unsigned short u) {
    return __uint_as_float(((unsigned)u) << 16);
}

// Blocked transposed-weight layout (bf16): WT[k>>5][n][k&31], tile = 8192 elems (16KB).
#define OFF_XIJ1 0        // K=64  : tiles 0..1
#define OFF_XIJ2 16384    // K=256 : tiles 2..9
#define OFF_XCN1 81920    // tiles 10..11
#define OFF_XCN2 98304    // tiles 12..19
#define OFF_XCN3 163840   // tiles 20..27
#define OFF_LIN1 229376   // tiles 28..35
#define WT_TOTAL 294912
#define NTILES   36

__host__ __device__ constexpr int tile_off(int t) {
    return t < 2  ? OFF_XIJ1 + t * 8192
         : t < 10 ? OFF_XIJ2 + (t - 2) * 8192
         : t < 12 ? OFF_XCN1 + (t - 10) * 8192
         : t < 20 ? OFF_XCN2 + (t - 12) * 8192
         : t < 28 ? OFF_XCN3 + (t - 20) * 8192
         :          OFF_LIN1 + (t - 28) * 8192;
}

// ---- async global->LDS (LDS dest = wave-uniform base + lane*16B) ----
__device__ __forceinline__ void gll16(const unsigned short* g, unsigned short* l) {
    __builtin_amdgcn_global_load_lds(
        (const __attribute__((address_space(1))) unsigned int*)g,
        (__attribute__((address_space(3))) unsigned int*)l, 16, 0, 0);
}
// 16KB weight tile with 256 threads: 4 gll16/thread (vmcnt cost 4/wave)
__device__ __forceinline__ void stage_tile(const unsigned short* g, unsigned short* l,
                                           int tid, int wv) {
#pragma unroll
    for (int c = 0; c < 4; ++c)
        gll16(g + c * 2048 + tid * 8, l + c * 2048 + wv * 512);
}
// 8KB activation tile (64x64 bf16) with 256 threads: 2 gll16/thread
__device__ __forceinline__ void stage_act(const unsigned short* g, unsigned short* l,
                                          int tid, int wv) {
#pragma unroll
    for (int c = 0; c < 2; ++c)
        gll16(g + c * 2048 + tid * 8, l + c * 2048 + wv * 512);
}

// Edge stage (1 edge per wave, latency TLP-hidden at 8192 blocks) + weight-prep piggyback.
// xij/xcn written PRE-SWIZZLED (elem ^= (row&7)<<3) so linear global_load_lds staging
// lands in the swizzled layout the mlp A-fragment ds_reads expect.
__global__ __launch_bounds__(256) void edge_prep_k(const float* __restrict__ x,
                                                   const int* __restrict__ adj,
                                                   const int* __restrict__ tar,
                                                   const float* __restrict__ xij_w1,
                                                   const float* __restrict__ xij_w2,
                                                   const float* __restrict__ xcn_w1,
                                                   const float* __restrict__ xcn_w2,
                                                   const float* __restrict__ xcn_w3,
                                                   const float* __restrict__ lin_w1,
                                                   unsigned short* __restrict__ WT,
                                                   unsigned short* __restrict__ xij_g,
                                                   unsigned short* __restrict__ xcn_g) {
    const int wv   = threadIdx.x >> 6;
    const int lane = threadIdx.x & 63;
    const int e    = blockIdx.x * 4 + wv;      // grid = NEDGES/4 = 8192

    int i = tar[e];
    int j = tar[NEDGES + e];
    int ni = adj[i * DDEG + lane];
    int nj = adj[j * DDEG + lane];
    float xi = x[i * FIN + lane];
    float xj = x[j * FIN + lane];

    bool found = false;
#pragma unroll
    for (int b = 0; b < 64; ++b)
        found |= (ni == (int)__builtin_amdgcn_readlane(nj, b));
    unsigned long long m = __ballot(found);

    float acc = 0.f;
    while (m) {
        int a = __ffsll(m) - 1;
        m &= m - 1;
        int r = (int)__builtin_amdgcn_readlane(ni, a);
        acc += x[r * FIN + lane];
    }
    int sl = lane ^ ((e & 7) << 3);            // pre-swizzle (row&7 == e&7)
    xij_g[(size_t)e * FIN + sl] = f2bf(xi * xj);
    xcn_g[(size_t)e * FIN + sl] = f2bf(acc);

    // ---- weight-prep piggyback: fp32 W[K,256] -> blocked bf16 WT ----
    if (blockIdx.x < WT_TOTAL / 256) {
        int idx = blockIdx.x * 256 + threadIdx.x;
        const float* src;
        int r;
        if (idx < OFF_XIJ2)      { r = idx - OFF_XIJ1; src = xij_w1; }
        else if (idx < OFF_XCN1) { r = idx - OFF_XIJ2; src = xij_w2; }
        else if (idx < OFF_XCN2) { r = idx - OFF_XCN1; src = xcn_w1; }
        else if (idx < OFF_XCN3) { r = idx - OFF_XCN2; src = xcn_w2; }
        else if (idx < OFF_LIN1) { r = idx - OFF_XCN3; src = xcn_w3; }
        else                     { r = idx - OFF_LIN1; src = lin_w1; }
        int kb  = r >> 13;
        int n   = (r & 8191) >> 5;
        int klo = r & 31;
        WT[idx] = f2bf(src[(kb * 32 + klo) * HID + n]);
    }
}

// One phase of the 36-tile stream; 2-slot ring, ONE barrier per tile-step.
// Step t: s_waitcnt vmcnt(0) lgkmcnt(0)  // tile t landed (staged at step t-1);
//                                        // own ds ops drained before barrier
//         s_barrier                      // all waves synced; WAR on slot (t+1)&1 safe
//                                        // (its readers ran at step t-1, drained above)
//         stage tile t+1 into slot (t+1)&1  [+ optional sX restage at phase entry]
//         ds_read B(4)+A(4); 16 MFMA (setprio)
// acc[4][4]: wave covers all 64 rows x cols col0..col0+64.
template <int T0, int NT, int LDA>
__device__ __forceinline__ void run_phase(const unsigned short* As,
                                          unsigned short* ring,
                                          const unsigned short* __restrict__ WT,
                                          const unsigned short* __restrict__ restage_src,
                                          unsigned short* sX,
                                          int lr, int lg, int col0,
                                          int tid, int wv, f32x4 acc[4][4]) {
#pragma unroll
    for (int m = 0; m < 4; ++m)
#pragma unroll
        for (int n = 0; n < 4; ++n) acc[m][n] = (f32x4){0.f, 0.f, 0.f, 0.f};
    const int sw = (lr & 7) << 3;
#pragma unroll
    for (int s = 0; s < NT; ++s) {
        const int t = T0 + s;
        asm volatile("s_waitcnt vmcnt(0) lgkmcnt(0)" ::: "memory");
        __builtin_amdgcn_s_barrier();
        if (t + 1 < NTILES)
            stage_tile(WT + tile_off(t + 1), ring + ((t + 1) & 1) * 8192, tid, wv);
        if (restage_src && s == 0)
            stage_act(restage_src, sX, tid, wv);   // sX readers fenced by this barrier
        const unsigned short* cur = ring + (t & 1) * 8192;
        bf16x8 a[4], b[4];
#pragma unroll
        for (int n = 0; n < 4; ++n)
            b[n] = *reinterpret_cast<const bf16x8*>(&cur[(col0 + n * 16 + lr) * 32 + 8 * lg]);
#pragma unroll
        for (int m = 0; m < 4; ++m)
            a[m] = *reinterpret_cast<const bf16x8*>(
                &As[(m * 16 + lr) * LDA + ((s * 32 + 8 * lg) ^ sw)]);
        __builtin_amdgcn_s_setprio(1);
#pragma unroll
        for (int m = 0; m < 4; ++m)
#pragma unroll
            for (int n = 0; n < 4; ++n)
                acc[m][n] = __builtin_amdgcn_mfma_f32_16x16x32_bf16(a[m], b[n], acc[m][n], 0, 0, 0);
        __builtin_amdgcn_s_setprio(0);
    }
}

// MLP over 64-edge tiles; 4 waves (256 thr); grid 512 = 2 INDEPENDENT blocks/CU
// (separate barrier domains -> one block's wait overlaps the other's compute).
// Wave wv: all 64 rows, cols col0 = wv*64..+64 (m4n4 fragments).
// D-frag lane l: row = m*16 + 4*(l>>4) + i, col = col0 + n*16 + (l&15).
// LDS 72 KB (8 sX + 32 sH + 32 ring) -> 2 blocks/CU by LDS; __launch_bounds__(256,2)
// -> 8 waves/CU -> 2 waves/SIMD -> VGPR cap 256: hij stays in registers, no spill.
__global__ __launch_bounds__(256, 2) void mlp_k(const unsigned short* __restrict__ xij_g,
                                                const unsigned short* __restrict__ xcn_g,
                                                const unsigned short* __restrict__ WT,
                                                const float* __restrict__ xij_b1,
                                                const float* __restrict__ xij_b2,
                                                const float* __restrict__ xcn_b1,
                                                const float* __restrict__ xcn_b2,
                                                const float* __restrict__ xcn_b3,
                                                const float* __restrict__ lin_b1,
                                                const float* __restrict__ lin_w2,
                                                const float* __restrict__ lin_b2,
                                                const float* __restrict__ beta,
                                                float* __restrict__ out) {
    __shared__ unsigned short sX[64 * 64];     // 8 KB: xij (P1), xcn (P3); sRed later
    __shared__ unsigned short sH[64 * 256];    // 32 KB activation (in-place reuse)
    __shared__ unsigned short sB[2 * 8192];    // 32 KB weight ring

    const int tid  = threadIdx.x;
    const int wv   = tid >> 6;
    const int lane = tid & 63;
    const int lr   = lane & 15;
    const int lg   = lane >> 4;
    const int col0 = wv * 64;
    const int row0 = blockIdx.x * 64;

    // prologue: sX<-xij (2) + tile0 (4) = 6 outstanding; P1 step0's vmcnt(0) drains.
    stage_act(xij_g + (size_t)row0 * FIN, sX, tid, wv);
    stage_tile(WT + tile_off(0), sB, tid, wv);
    const float betaf = beta[0];

    f32x4 acc[4][4];
    float bl[4];

    // ---- P1 (t=0,1): h1 = relu(xij @ xij_w1 + b1) -> sH ----
    run_phase<0, 2, 64>(sX, sB, WT, nullptr, nullptr, lr, lg, col0, tid, wv, acc);
#pragma unroll
    for (int n = 0; n < 4; ++n) bl[n] = xij_b1[col0 + n * 16 + lr];
#pragma unroll
    for (int m = 0; m < 4; ++m)
#pragma unroll
        for (int n = 0; n < 4; ++n)
#pragma unroll
            for (int i = 0; i < 4; ++i) {
                int row = m * 16 + 4 * lg + i;
                int col = col0 + n * 16 + lr;
                sH[row * HID + (col ^ ((row & 7) << 3))] = f2bf(fmaxf(acc[m][n][i] + bl[n], 0.f));
            }
    // writes drained+fenced at P2 step0's lgkm0+barrier before any wave reads sH

    // ---- P2 (t=2..9): h_ij = h1 @ xij_w2 + b2 -> registers (packed bf16, 32 VGPR);
    //      restages sX <- xcn at step0 (xij readers fenced by that barrier) ----
    run_phase<2, 8, 256>(sH, sB, WT, xcn_g + (size_t)row0 * FIN, sX, lr, lg, col0, tid, wv, acc);
#pragma unroll
    for (int n = 0; n < 4; ++n) bl[n] = xij_b2[col0 + n * 16 + lr];
    unsigned hij_lo[4][4], hij_hi[4][4];
#pragma unroll
    for (int m = 0; m < 4; ++m)
#pragma unroll
        for (int n = 0; n < 4; ++n) {
            hij_lo[m][n] = ((unsigned)f2bf(acc[m][n][1] + bl[n]) << 16) | f2bf(acc[m][n][0] + bl[n]);
            hij_hi[m][n] = ((unsigned)f2bf(acc[m][n][3] + bl[n]) << 16) | f2bf(acc[m][n][2] + bl[n]);
        }

    // ---- P3 (t=10,11): t1 = relu(xcn @ xcn_w1 + b1) -> sH (P2 sH reads fenced by
    //      P3 step0's lgkm0+barrier before this epilogue's writes land) ----
    run_phase<10, 2, 64>(sX, sB, WT, nullptr, nullptr, lr, lg, col0, tid, wv, acc);
#pragma unroll
    for (int n = 0; n < 4; ++n) bl[n] = xcn_b1[col0 + n * 16 + lr];
#pragma unroll
    for (int m = 0; m < 4; ++m)
#pragma unroll
        for (int n = 0; n < 4; ++n)
#pragma unroll
            for (int i = 0; i < 4; ++i) {
                int row = m * 16 + 4 * lg + i;
                int col = col0 + n * 16 + lr;
                sH[row * HID + (col ^ ((row & 7) << 3))] = f2bf(fmaxf(acc[m][n][i] + bl[n], 0.f));
            }

    // ---- P4 (t=12..19): t2 = relu(t1 @ xcn_w2 + b2) -> sH IN PLACE ----
    run_phase<12, 8, 256>(sH, sB, WT, nullptr, nullptr, lr, lg, col0, tid, wv, acc);
    asm volatile("s_waitcnt lgkmcnt(0)" ::: "memory");
    __builtin_amdgcn_s_barrier();   // all waves' t1 reads done before overwrite
#pragma unroll
    for (int n = 0; n < 4; ++n) bl[n] = xcn_b2[col0 + n * 16 + lr];
#pragma unroll
    for (int m = 0; m < 4; ++m)
#pragma unroll
        for (int n = 0; n < 4; ++n)
#pragma unroll
            for (int i = 0; i < 4; ++i) {
                int row = m * 16 + 4 * lg + i;
                int col = col0 + n * 16 + lr;
                sH[row * HID + (col ^ ((row & 7) << 3))] = f2bf(fmaxf(acc[m][n][i] + bl[n], 0.f));
            }

    // ---- P5 (t=20..27): u = (t2 @ xcn_w3 + b3) * beta + h_ij -> sH IN PLACE ----
    run_phase<20, 8, 256>(sH, sB, WT, nullptr, nullptr, lr, lg, col0, tid, wv, acc);
    asm volatile("s_waitcnt lgkmcnt(0)" ::: "memory");
    __builtin_amdgcn_s_barrier();
#pragma unroll
    for (int n = 0; n < 4; ++n) bl[n] = xcn_b3[col0 + n * 16 + lr];
#pragma unroll
    for (int m = 0; m < 4; ++m)
#pragma unroll
        for (int n = 0; n < 4; ++n) {
            float h0 = b2f((unsigned short)(hij_lo[m][n] & 0xFFFF));
            float h1 = b2f((unsigned short)(hij_lo[m][n] >> 16));
            float h2 = b2f((unsigned short)(hij_hi[m][n] & 0xFFFF));
            float h3 = b2f((unsigned short)(hij_hi[m][n] >> 16));
            float v0 = (acc[m][n][0] + bl[n]) * betaf + h0;
            float v1 = (acc[m][n][1] + bl[n]) * betaf + h1;
            float v2 = (acc[m][n][2] + bl[n]) * betaf + h2;
            float v3 = (acc[m][n][3] + bl[n]) * betaf + h3;
            int rb = m * 16 + 4 * lg;
            int col = col0 + n * 16 + lr;
            sH[(rb + 0) * HID + (col ^ (((rb + 0) & 7) << 3))] = f2bf(v0);
            sH[(rb + 1) * HID + (col ^ (((rb + 1) & 7) << 3))] = f2bf(v1);
            sH[(rb + 2) * HID + (col ^ (((rb + 2) & 7) << 3))] = f2bf(v2);
            sH[(rb + 3) * HID + (col ^ (((rb + 3) & 7) << 3))] = f2bf(v3);
        }

    // ---- P6 (t=28..35): out = relu(u @ lin_w1 + lb1) . lin_w2 + lb2 ----
    run_phase<28, 8, 256>(sH, sB, WT, nullptr, nullptr, lr, lg, col0, tid, wv, acc);
#pragma unroll
    for (int n = 0; n < 4; ++n) bl[n] = lin_b1[col0 + n * 16 + lr];
    float w2l[4];
#pragma unroll
    for (int n = 0; n < 4; ++n) w2l[n] = lin_w2[col0 + n * 16 + lr];
    float* sRed = (float*)sX;   // sX dead since P3; 4 col-groups x 64 rows f32 (1 KB)
#pragma unroll
    for (int m = 0; m < 4; ++m) {
        float p[4] = {0.f, 0.f, 0.f, 0.f};
#pragma unroll
        for (int n = 0; n < 4; ++n)
#pragma unroll
            for (int i = 0; i < 4; ++i)
                p[i] += fmaxf(acc[m][n][i] + bl[n], 0.f) * w2l[n];
#pragma unroll
        for (int i = 0; i < 4; ++i) {
            float s = p[i];
            s += __shfl_xor(s, 1);
            s += __shfl_xor(s, 2);
            s += __shfl_xor(s, 4);
            s += __shfl_xor(s, 8);
            if (lr == 0) sRed[wv * 64 + m * 16 + 4 * lg + i] = s;
        }
    }
    __syncthreads();   // stream fully drained (no loads outstanding after t=35)
    if (tid < 64)
        out[row0 + tid] = sRed[tid] + sRed[64 + tid] + sRed[128 + tid] + sRed[192 + tid] + lin_b2[0];
}

extern "C" void kernel_launch(void* const* d_in, const int* in_sizes, int n_in,
                              void* d_out, int out_size, void* d_ws, size_t ws_size,
                              hipStream_t stream) {
    const float* x      = (const float*)d_in[0];
    const int*   adj    = (const int*)d_in[1];
    const int*   tar    = (const int*)d_in[2];
    const float* beta   = (const float*)d_in[3];
    const float* xcn_w1 = (const float*)d_in[4];
    const float* xcn_b1 = (const float*)d_in[5];
    const float* xcn_w2 = (const float*)d_in[6];
    const float* xcn_b2 = (const float*)d_in[7];
    const float* xcn_w3 = (const float*)d_in[8];
    const float* xcn_b3 = (const float*)d_in[9];
    const float* xij_w1 = (const float*)d_in[10];
    const float* xij_b1 = (const float*)d_in[11];
    const float* xij_w2 = (const float*)d_in[12];
    const float* xij_b2 = (const float*)d_in[13];
    const float* lin_w1 = (const float*)d_in[14];
    const float* lin_b1 = (const float*)d_in[15];
    const float* lin_w2 = (const float*)d_in[16];
    const float* lin_b2 = (const float*)d_in[17];

    unsigned short* WT    = (unsigned short*)d_ws;                     // 576 KiB
    unsigned short* xij_g = (unsigned short*)((char*)d_ws + 589824);   // 4 MiB
    unsigned short* xcn_g = (unsigned short*)((char*)d_ws + 4784128);  // 4 MiB

    edge_prep_k<<<NEDGES / 4, 256, 0, stream>>>(x, adj, tar,
                                                xij_w1, xij_w2, xcn_w1, xcn_w2, xcn_w3, lin_w1,
                                                WT, xij_g, xcn_g);
    mlp_k<<<NEDGES / 64, 256, 0, stream>>>(xij_g, xcn_g, WT,
                                           xij_b1, xij_b2, xcn_b1, xcn_b2, xcn_b3,
                                           lin_b1, lin_w2, lin_b2, beta, (float*)d_out);
}